// Round 4
// baseline (2525005.664 us; speedup 1.0000x reference)
//
#include <hip/hip_runtime.h>

// ---------------- problem constants ----------------
#define SEQ   601
#define NB    512
#define NCL   8          // clusters (one per XCD: cl = blockIdx & 7 under SPX round-robin)
#define WPC   32         // workgroups per cluster
#define BCL   64         // batch rows per cluster

typedef _Float16 f16;
typedef _Float16 f16x8 __attribute__((ext_vector_type(8)));
typedef _Float16 f16x4 __attribute__((ext_vector_type(4)));
typedef float    f32x4 __attribute__((ext_vector_type(4)));
typedef unsigned int u32;

// ---------------- workspace layout (bytes) ----------------
// [0, 16K)                 flags: [8 cl][32 wg], each flag on its own 64B line
// 16K + cl*CLSTRIDE:
//    +0      x_buf   [64][256] f16        32K
//    +32K    h1_buf  [2][64][256] f16     64K
//    +96K    h2_buf  [2][64][256] f16     64K
//    +160K   partial [64 slots][5][64] f32 80K
#define CLSTRIDE   (245760)
#define CTRL_BYTES (16*1024 + NCL*CLSTRIDE)      // 1,982,464 — memset each launch
#define ZPROJ_OFF  (2*1024*1024)                 // zproj: [512*601][256] f16 = 157.5MB

// ---------------- fast math ----------------
__device__ __forceinline__ float fsig(float x) {
  return 1.0f / (1.0f + __expf(-x));
}
__device__ __forceinline__ float ftanh(float x) {
  // 1 - 2/(exp(2x)+1); saturates correctly for large |x|
  return 1.0f - 2.0f / (__expf(2.0f * x) + 1.0f);
}

// ---------------- cluster barrier (XCD-local, no L2 writeback) ----------------
// All WGs of a cluster share one XCD's L2 (cl = blockIdx&7 under SPX dispatch).
// Protocol:
//   - data stores: plain (write-through L1 -> local L2); __syncthreads drains vmcnt.
//   - flag store:  workgroup-scope relaxed atomic -> plain global_store into local L2.
//   - flag poll:   sc0 load (bypass L1, read local L2) — a plain load would spin on
//                  a stale L1 line forever.
//   - after join:  ACQUIRE-agent fence only (buffer_inv: L1 + remote-L2-line inv,
//                  NO dirty writeback). The round-1 RELEASE fence's buffer_wbl2
//                  (full dirty-L2 flush to HBM, 1.24 GB/dispatch) is gone.
// Flags zeroed by hipMemsetAsync before launch, so 0xAA poison can't false-release.
__device__ __forceinline__ void cluster_barrier(u32* flags, int cl, int wg,
                                                u32 phase, int tid) {
  __syncthreads();   // all threads' data stores drained to L2 (vmcnt 0 before s_barrier)
  if (tid == 0)
    __hip_atomic_store(&flags[(cl * 32 + wg) * 16], phase,
                       __ATOMIC_RELAXED, __HIP_MEMORY_SCOPE_WORKGROUP);
  if (tid < 32) {
    const u32* fp = &flags[(cl * 32 + tid) * 16];
    u32 v = 0;
    int guard = 0;
    do {
      asm volatile("global_load_dword %0, %1, off sc0\n\t"
                   "s_waitcnt vmcnt(0)"
                   : "=v"(v) : "v"(fp) : "memory");
      if (v >= phase) break;
      __builtin_amdgcn_s_sleep(1);
    } while (++guard < (1 << 14));   // fail fast if XCD mapping assumption is wrong
  }
  __syncthreads();   // join pollers before anyone invalidates + reads
  __builtin_amdgcn_fence(__ATOMIC_ACQUIRE, "agent");  // buffer_inv (no writeback)
}

// ---------------- zproj kernel ----------------
// zproj[col][row] = sum_k fc1_w[row][k] * z[col][k],  col = b*601 + t, k < 100.
// One-shot MFMA GEMM: M=256, K=100 (padded to 128 with zero W rows / masked z),
// N = 307712 cols. Grid: 4808 WGs x 256 thr; each wave owns 16 cols.
__global__ __launch_bounds__(256) void zproj_kernel(
    const float* __restrict__ z, const float* __restrict__ fc1_w,
    f16* __restrict__ zp)
{
  const int wv = threadIdx.x >> 6, l = threadIdx.x & 63;
  const int hi = l >> 4, lr = l & 15;
  const long col = (long)blockIdx.x * 64 + wv * 16 + lr;

  // B-fragments from z (lane: col = l&15, k = 32*ks + 8*(l>>4) + j)
  f16x8 zf[4];
  {
    const float* zr = z + col * 100;
    #pragma unroll
    for (int ks = 0; ks < 4; ++ks) {
      const int kb = ks * 32 + hi * 8;
      f16x8 v;
      #pragma unroll
      for (int j = 0; j < 8; ++j) {
        const int k = kb + j;
        float x = (k < 100) ? zr[k] : 0.0f;   // masked: never OOB, padded K=0 terms
        v[j] = (f16)x;
      }
      zf[ks] = v;
    }
  }

  f32x4 acc[16];
  #pragma unroll
  for (int mt = 0; mt < 16; ++mt) acc[mt] = (f32x4){0.f, 0.f, 0.f, 0.f};

  #pragma unroll
  for (int mt = 0; mt < 16; ++mt) {
    const int row = mt * 16 + lr;           // A-frag: row = l&15 (+16*mt)
    const float* wr = fc1_w + row * 105;    // fc1_w is [256][105]; cols 0..99 = z part
    #pragma unroll
    for (int ks = 0; ks < 4; ++ks) {
      const int kb = ks * 32 + hi * 8;
      f16x8 wf;
      #pragma unroll
      for (int j = 0; j < 8; ++j) {
        const int k = kb + j;
        float x = (k < 100) ? wr[k] : 0.0f; // mask out prev-part cols & pad
        wf[j] = (f16)x;
      }
      acc[mt] = __builtin_amdgcn_mfma_f32_16x16x32_f16(wf, zf[ks], acc[mt], 0, 0, 0);
    }
  }

  // C layout: col = l&15 (same col), row = 16*mt + 4*(l>>4) + reg  (4 contiguous rows)
  f16* outp = zp + col * 256;
  #pragma unroll
  for (int mt = 0; mt < 16; ++mt) {
    f16x4 v;
    v[0] = (f16)acc[mt][0]; v[1] = (f16)acc[mt][1];
    v[2] = (f16)acc[mt][2]; v[3] = (f16)acc[mt][3];
    *(f16x4*)(outp + mt * 16 + hi * 4) = v;
  }
}

// ---------------- main persistent recurrence kernel ----------------
// 256 WGs x 256 thr (all co-resident: ~4.3KB LDS, 1 WG/CU).
// cluster = blockIdx & 7 (XCD), wg = blockIdx >> 3.
// Each WG owns 8 hidden units for both cells; gate rows ordered [4*j + gamma]
// (gamma = i,f,g,o) so each lane's 4 acc regs = 4 gates of one hid.
// Waves: wv = (m, nh): m-tile (16 rows) x two 16-batch n-tiles.
// All LSTM weights live in VGPRs as pre-packed f16 MFMA A-fragments.
__global__ __launch_bounds__(256, 1) void rnn_kernel(
    const float* __restrict__ prev_gen,
    const float* __restrict__ fc1_w, const float* __restrict__ fc1_b,
    const float* __restrict__ w_ih1, const float* __restrict__ w_hh1,
    const float* __restrict__ b_ih1, const float* __restrict__ b_hh1,
    const float* __restrict__ w_ih2, const float* __restrict__ w_hh2,
    const float* __restrict__ b_ih2, const float* __restrict__ b_hh2,
    const float* __restrict__ fc2_w, const float* __restrict__ fc2_b,
    float* __restrict__ out, char* ws)
{
  const int cl = blockIdx.x & 7, wg = blockIdx.x >> 3;
  const int tid = threadIdx.x;
  const int wv = tid >> 6, l = tid & 63;
  const int m = wv >> 1, nh = wv & 1;
  const int hi = l >> 4, lr = l & 15;
  const int nt0 = nh * 2, nt1 = nh * 2 + 1;

  u32* flags = (u32*)ws;
  char* cbase = ws + 16 * 1024 + cl * CLSTRIDE;
  f16*   xb   = (f16*)(cbase);
  f16*   h1b  = (f16*)(cbase + 32 * 1024);
  f16*   h2b  = (f16*)(cbase + 96 * 1024);
  float* part = (float*)(cbase + 160 * 1024);
  const f16* zp = (const f16*)(ws + ZPROJ_OFF);

  // ----- static per-thread data -----
  const int hid_loc = m * 4 + hi;            // 0..7 within WG
  const int H = wg * 8 + hid_loc;            // absolute hid
  const int r_loc = m * 16 + lr;             // local gate row (A-frag row)
  const int R = (r_loc & 3) * 256 + wg * 8 + (r_loc >> 2);  // abs gate row (i|f|g|o blocks)

  f16x8 w1f[16], w2f[16];                    // K=512 -> 16 ksteps, 4 VGPR each
  #pragma unroll
  for (int ks = 0; ks < 16; ++ks) {
    const int ko = (ks & 7) * 32 + hi * 8;
    const float* s1 = (ks < 8) ? (w_ih1 + R * 256 + ko) : (w_hh1 + R * 256 + ko);
    const float* s2 = (ks < 8) ? (w_ih2 + R * 256 + ko) : (w_hh2 + R * 256 + ko);
    f16x8 a, b;
    #pragma unroll
    for (int j = 0; j < 8; ++j) { a[j] = (f16)s1[j]; b[j] = (f16)s2[j]; }
    w1f[ks] = a; w2f[ks] = b;
  }

  float bs1[4], bs2[4];
  #pragma unroll
  for (int gg = 0; gg < 4; ++gg) {
    bs1[gg] = b_ih1[gg * 256 + H] + b_hh1[gg * 256 + H];
    bs2[gg] = b_ih2[gg * 256 + H] + b_hh2[gg * 256 + H];
  }
  float f2w[5];
  #pragma unroll
  for (int r = 0; r < 5; ++r) f2w[r] = fc2_w[r * 256 + H];

  // stage-C thread mapping
  const int bC = tid & 63, rgC = tid >> 6;
  float w1p[2][5], b1c[2];
  #pragma unroll
  for (int rr = 0; rr < 2; ++rr) {
    const int xr = wg * 8 + rgC * 2 + rr;
    #pragma unroll
    for (int p = 0; p < 5; ++p) w1p[rr][p] = fc1_w[xr * 105 + 100 + p];
    b1c[rr] = fc1_b[xr];
  }

  __shared__ alignas(16) f16 hstage[64][8];   // reused for h1 / h2 / x staging
  __shared__ float prevlds[5][64];

  float c1a = 0.f, c1b = 0.f, c2a = 0.f, c2b = 0.f;
  const int bbase = cl * 64;
  u32 phase = 0;

  for (int t = 0; t < SEQ; ++t) {
    // ================= stage C: prev_{t-1} + x_t =================
    if (t == 0) {
      prevlds[rgC][bC] = prev_gen[(bbase + bC) * 5 + rgC];
      if (rgC == 0) prevlds[4][bC] = prev_gen[(bbase + bC) * 5 + 4];
    } else {
      float s = 0.f;
      #pragma unroll 8
      for (int p = 0; p < 64; ++p) s += part[(p * 5 + rgC) * 64 + bC];
      s = ftanh(s + fc2_b[rgC]);
      prevlds[rgC][bC] = s;
      if (wg == 0) out[((long)(bbase + bC) * SEQ + (t - 1)) * 5 + rgC] = s;
      if (rgC == 0) {
        float s4 = 0.f;
        #pragma unroll 8
        for (int p = 0; p < 64; ++p) s4 += part[(p * 5 + 4) * 64 + bC];
        s4 = ftanh(s4 + fc2_b[4]);
        prevlds[4][bC] = s4;
        if (wg == 0) out[((long)(bbase + bC) * SEQ + (t - 1)) * 5 + 4] = s4;
      }
    }
    __syncthreads();
    {
      const f16* zrow = zp + ((long)(bbase + bC) * SEQ + t) * 256 + wg * 8 + rgC * 2;
      float pv[5];
      #pragma unroll
      for (int p = 0; p < 5; ++p) pv[p] = prevlds[p][bC];
      #pragma unroll
      for (int rr = 0; rr < 2; ++rr) {
        float v = (float)zrow[rr] + b1c[rr];
        #pragma unroll
        for (int p = 0; p < 5; ++p) v += w1p[rr][p] * pv[p];
        hstage[bC][rgC * 2 + rr] = (f16)fmaxf(v, 0.f);
      }
    }
    __syncthreads();
    if (tid < 64)
      *(f16x8*)(xb + tid * 256 + wg * 8) = *(const f16x8*)hstage[tid];
    cluster_barrier(flags, cl, wg, ++phase, tid);

    // ================= stage A: gates1 -> h1_t =================
    {
      const f16* hprev = h1b + ((t + 1) & 1) * (64 * 256);
      f32x4 acc0 = {0.f, 0.f, 0.f, 0.f}, acc1 = {0.f, 0.f, 0.f, 0.f};
      #pragma unroll
      for (int ks = 0; ks < 16; ++ks) {
        const f16* src = (ks < 8) ? xb : hprev;
        const int koff = (ks & 7) * 32 + hi * 8;
        f16x8 b0 = *(const f16x8*)(src + (nt0 * 16 + lr) * 256 + koff);
        f16x8 b1 = *(const f16x8*)(src + (nt1 * 16 + lr) * 256 + koff);
        acc0 = __builtin_amdgcn_mfma_f32_16x16x32_f16(w1f[ks], b0, acc0, 0, 0, 0);
        acc1 = __builtin_amdgcn_mfma_f32_16x16x32_f16(w1f[ks], b1, acc1, 0, 0, 0);
      }
      float i0 = fsig(acc0[0] + bs1[0]), f0 = fsig(acc0[1] + bs1[1]);
      float g0 = ftanh(acc0[2] + bs1[2]), o0 = fsig(acc0[3] + bs1[3]);
      c1a = f0 * c1a + i0 * g0;
      hstage[nt0 * 16 + lr][hid_loc] = (f16)(o0 * ftanh(c1a));
      float i1 = fsig(acc1[0] + bs1[0]), f1 = fsig(acc1[1] + bs1[1]);
      float g1 = ftanh(acc1[2] + bs1[2]), o1 = fsig(acc1[3] + bs1[3]);
      c1b = f1 * c1b + i1 * g1;
      hstage[nt1 * 16 + lr][hid_loc] = (f16)(o1 * ftanh(c1b));
    }
    __syncthreads();
    if (tid < 64)
      *(f16x8*)(h1b + (t & 1) * (64 * 256) + tid * 256 + wg * 8) = *(const f16x8*)hstage[tid];
    cluster_barrier(flags, cl, wg, ++phase, tid);

    // ================= stage B: gates2 -> h2_t + fc2 partials =================
    {
      const f16* h1cur  = h1b + (t & 1) * (64 * 256);
      const f16* h2prev = h2b + ((t + 1) & 1) * (64 * 256);
      f32x4 acc0 = {0.f, 0.f, 0.f, 0.f}, acc1 = {0.f, 0.f, 0.f, 0.f};
      #pragma unroll
      for (int ks = 0; ks < 16; ++ks) {
        const f16* src = (ks < 8) ? h1cur : h2prev;
        const int koff = (ks & 7) * 32 + hi * 8;
        f16x8 b0 = *(const f16x8*)(src + (nt0 * 16 + lr) * 256 + koff);
        f16x8 b1 = *(const f16x8*)(src + (nt1 * 16 + lr) * 256 + koff);
        acc0 = __builtin_amdgcn_mfma_f32_16x16x32_f16(w2f[ks], b0, acc0, 0, 0, 0);
        acc1 = __builtin_amdgcn_mfma_f32_16x16x32_f16(w2f[ks], b1, acc1, 0, 0, 0);
      }
      float i0 = fsig(acc0[0] + bs2[0]), f0 = fsig(acc0[1] + bs2[1]);
      float g0 = ftanh(acc0[2] + bs2[2]), o0 = fsig(acc0[3] + bs2[3]);
      c2a = f0 * c2a + i0 * g0;
      float hv0 = o0 * ftanh(c2a);
      float i1 = fsig(acc1[0] + bs2[0]), f1 = fsig(acc1[1] + bs2[1]);
      float g1 = ftanh(acc1[2] + bs2[2]), o1 = fsig(acc1[3] + bs2[3]);
      c2b = f1 * c2b + i1 * g1;
      float hv1 = o1 * ftanh(c2b);
      hstage[nt0 * 16 + lr][hid_loc] = (f16)hv0;
      hstage[nt1 * 16 + lr][hid_loc] = (f16)hv1;

      // fc2 partials from fp32 register h2 (full output precision path)
      float p0[5], p1[5];
      #pragma unroll
      for (int r = 0; r < 5; ++r) { p0[r] = f2w[r] * hv0; p1[r] = f2w[r] * hv1; }
      #pragma unroll
      for (int r = 0; r < 5; ++r) {   // reduce over the 4 hid-lanes (l^16, l^32)
        p0[r] += __shfl_xor(p0[r], 16); p0[r] += __shfl_xor(p0[r], 32);
        p1[r] += __shfl_xor(p1[r], 16); p1[r] += __shfl_xor(p1[r], 32);
      }
      if (hi == 0) {
        const int slot = wg * 2 + m;   // 64 slots; (m,nh=0/1) write disjoint cols
        #pragma unroll
        for (int r = 0; r < 5; ++r) {
          part[(slot * 5 + r) * 64 + nt0 * 16 + lr] = p0[r];
          part[(slot * 5 + r) * 64 + nt1 * 16 + lr] = p1[r];
        }
      }
    }
    __syncthreads();
    if (tid < 64)
      *(f16x8*)(h2b + (t & 1) * (64 * 256) + tid * 256 + wg * 8) = *(const f16x8*)hstage[tid];
    cluster_barrier(flags, cl, wg, ++phase, tid);
  }

  // ================= final output: prev_600 =================
  {
    float s = 0.f;
    #pragma unroll 8
    for (int p = 0; p < 64; ++p) s += part[(p * 5 + rgC) * 64 + bC];
    s = ftanh(s + fc2_b[rgC]);
    if (wg == 0) out[((long)(bbase + bC) * SEQ + (SEQ - 1)) * 5 + rgC] = s;
    if (rgC == 0) {
      float s4 = 0.f;
      #pragma unroll 8
      for (int p = 0; p < 64; ++p) s4 += part[(p * 5 + 4) * 64 + bC];
      s4 = ftanh(s4 + fc2_b[4]);
      if (wg == 0) out[((long)(bbase + bC) * SEQ + (SEQ - 1)) * 5 + 4] = s4;
    }
  }
}

// ---------------- launcher ----------------
extern "C" void kernel_launch(void* const* d_in, const int* in_sizes, int n_in,
                              void* d_out, int out_size, void* d_ws, size_t ws_size,
                              hipStream_t stream)
{
  const float* z     = (const float*)d_in[0];
  const float* prevg = (const float*)d_in[1];
  const float* fc1_w = (const float*)d_in[2];
  const float* fc1_b = (const float*)d_in[3];
  const float* w_ih1 = (const float*)d_in[4];
  const float* w_hh1 = (const float*)d_in[5];
  const float* b_ih1 = (const float*)d_in[6];
  const float* b_hh1 = (const float*)d_in[7];
  const float* w_ih2 = (const float*)d_in[8];
  const float* w_hh2 = (const float*)d_in[9];
  const float* b_ih2 = (const float*)d_in[10];
  const float* b_hh2 = (const float*)d_in[11];
  const float* fc2_w = (const float*)d_in[12];
  const float* fc2_b = (const float*)d_in[13];
  float* out = (float*)d_out;
  char*  ws  = (char*)d_ws;

  // zero flags + exchange buffers (h_{-1}=0, and kills the 0xAA poison)
  hipMemsetAsync(ws, 0, CTRL_BYTES, stream);

  f16* zproj = (f16*)(ws + ZPROJ_OFF);
  // 512*601 cols / 64 cols-per-WG = 4808 exactly
  zproj_kernel<<<dim3(4808), dim3(256), 0, stream>>>(z, fc1_w, zproj);

  rnn_kernel<<<dim3(256), dim3(256), 0, stream>>>(
      prevg, fc1_w, fc1_b, w_ih1, w_hh1, b_ih1, b_hh1,
      w_ih2, w_hh2, b_ih2, b_hh2, fc2_w, fc2_b, out, ws);
}

// Round 5
// 24707.259 us; speedup vs baseline: 102.1969x; 102.1969x over previous
//
#include <hip/hip_runtime.h>

// ---------------- problem constants ----------------
#define SEQ   601
#define NB    512
#define NCL   8          // clusters
#define WPC   32         // workgroups per cluster
#define BCL   64         // batch rows per cluster

typedef _Float16 f16;
typedef _Float16 f16x8 __attribute__((ext_vector_type(8)));
typedef _Float16 f16x4 __attribute__((ext_vector_type(4)));
typedef float    f32x4 __attribute__((ext_vector_type(4)));
typedef unsigned int u32;
typedef unsigned long long u64;

// ---------------- workspace layout (bytes) ----------------
// [0, 16K)                 flags: [8 cl][32 wg], each flag on its own 64B line
// 16K + cl*CLSTRIDE:
//    +0      x_buf   [64][256] f16        32K
//    +32K    h1_buf  [2][64][256] f16     64K
//    +96K    h2_buf  [2][64][256] f16     64K
//    +160K   partial [64 slots][5][64] f32 80K
#define CLSTRIDE   (245760)
#define CTRL_BYTES (16*1024 + NCL*CLSTRIDE)      // memset each launch
#define ZPROJ_OFF  (2*1024*1024)                 // zproj: [512*601][256] f16 = 157.5MB

// ---------------- fast math ----------------
__device__ __forceinline__ float fsig(float x) {
  return 1.0f / (1.0f + __expf(-x));
}
__device__ __forceinline__ float ftanh(float x) {
  return 1.0f - 2.0f / (__expf(2.0f * x) + 1.0f);
}

// ---------------- coherence-point (MALL) push stores ----------------
// Relaxed agent-scope atomic store == global_store ... sc0 sc1 (write-through
// past the XCD-local L2 to the device coherence point), with NO fence emitted
// (relaxed ordering -> no buffer_wbl2). R1 measured the full-L2-writeback cost
// of the fence path (1.24 GB/dispatch); R4 measured that workgroup-scope
// stores are invisible across WGs (poll timeout = 1.4 ms/barrier). This is
// the surgical middle: only the ~KB of exchange data crosses to MALL.
__device__ __forceinline__ void push_u64(u64* p, u64 v) {
  __hip_atomic_store(p, v, __ATOMIC_RELAXED, __HIP_MEMORY_SCOPE_AGENT);
}
__device__ __forceinline__ void push_f32(float* p, float v) {
  __hip_atomic_store(p, v, __ATOMIC_RELAXED, __HIP_MEMORY_SCOPE_AGENT);
}
__device__ __forceinline__ void push_f16x8(f16* dst, const f16* src_lds) {
  u64 lo, hi;
  __builtin_memcpy(&lo, src_lds, 8);
  __builtin_memcpy(&hi, src_lds + 4, 8);
  push_u64((u64*)dst, lo);
  push_u64((u64*)dst + 1, hi);
}

// ---------------- cluster barrier (MALL-coherent) ----------------
// Writer: data already pushed with sc1 stores; __syncthreads drains vmcnt
// (sc1 store ack = visible at coherence point) -> flag pushed sc1.
// Poller: relaxed agent-scope atomic load (sc1 -> reads MALL, never a stale
// local line). Join -> acquire-agent fence (buffer_inv, invalidate-only, no
// writeback) so subsequent plain loads of exchange buffers refetch fresh lines.
__device__ __forceinline__ void cluster_barrier(u32* flags, int cl, int wg,
                                                u32 phase, int tid) {
  __syncthreads();   // every thread's sc1 data stores acked at coherence point
  if (tid == 0)
    __hip_atomic_store(&flags[(cl * 32 + wg) * 16], phase,
                       __ATOMIC_RELAXED, __HIP_MEMORY_SCOPE_AGENT);
  if (tid < 32) {
    const u32* fp = &flags[(cl * 32 + tid) * 16];
    int guard = 0;
    while (__hip_atomic_load(fp, __ATOMIC_RELAXED, __HIP_MEMORY_SCOPE_AGENT)
           < phase) {
      __builtin_amdgcn_s_sleep(1);
      if (++guard >= (1 << 14)) break;   // fail-fast tripwire, not a sync mechanism
    }
  }
  __syncthreads();   // join pollers before anyone invalidates + reads
  __builtin_amdgcn_fence(__ATOMIC_ACQUIRE, "agent");  // buffer_inv (no writeback)
}

// ---------------- zproj kernel ----------------
// zproj[col][row] = sum_k fc1_w[row][k] * z[col][k],  col = b*601 + t, k < 100.
__global__ __launch_bounds__(256) void zproj_kernel(
    const float* __restrict__ z, const float* __restrict__ fc1_w,
    f16* __restrict__ zp)
{
  const int wv = threadIdx.x >> 6, l = threadIdx.x & 63;
  const int hi = l >> 4, lr = l & 15;
  const long col = (long)blockIdx.x * 64 + wv * 16 + lr;

  f16x8 zf[4];
  {
    const float* zr = z + col * 100;
    #pragma unroll
    for (int ks = 0; ks < 4; ++ks) {
      const int kb = ks * 32 + hi * 8;
      f16x8 v;
      #pragma unroll
      for (int j = 0; j < 8; ++j) {
        const int k = kb + j;
        float x = (k < 100) ? zr[k] : 0.0f;
        v[j] = (f16)x;
      }
      zf[ks] = v;
    }
  }

  f32x4 acc[16];
  #pragma unroll
  for (int mt = 0; mt < 16; ++mt) acc[mt] = (f32x4){0.f, 0.f, 0.f, 0.f};

  #pragma unroll
  for (int mt = 0; mt < 16; ++mt) {
    const int row = mt * 16 + lr;
    const float* wr = fc1_w + row * 105;
    #pragma unroll
    for (int ks = 0; ks < 4; ++ks) {
      const int kb = ks * 32 + hi * 8;
      f16x8 wf;
      #pragma unroll
      for (int j = 0; j < 8; ++j) {
        const int k = kb + j;
        float x = (k < 100) ? wr[k] : 0.0f;
        wf[j] = (f16)x;
      }
      acc[mt] = __builtin_amdgcn_mfma_f32_16x16x32_f16(wf, zf[ks], acc[mt], 0, 0, 0);
    }
  }

  f16* outp = zp + col * 256;
  #pragma unroll
  for (int mt = 0; mt < 16; ++mt) {
    f16x4 v;
    v[0] = (f16)acc[mt][0]; v[1] = (f16)acc[mt][1];
    v[2] = (f16)acc[mt][2]; v[3] = (f16)acc[mt][3];
    *(f16x4*)(outp + mt * 16 + hi * 4) = v;
  }
}

// ---------------- main persistent recurrence kernel ----------------
// 256 WGs x 256 thr, 1 WG/CU. cluster = blockIdx & 7, wg = blockIdx >> 3.
// Each WG owns 8 hidden units; weights live in VGPRs as f16 MFMA A-fragments.
__global__ __launch_bounds__(256, 1) void rnn_kernel(
    const float* __restrict__ prev_gen,
    const float* __restrict__ fc1_w, const float* __restrict__ fc1_b,
    const float* __restrict__ w_ih1, const float* __restrict__ w_hh1,
    const float* __restrict__ b_ih1, const float* __restrict__ b_hh1,
    const float* __restrict__ w_ih2, const float* __restrict__ w_hh2,
    const float* __restrict__ b_ih2, const float* __restrict__ b_hh2,
    const float* __restrict__ fc2_w, const float* __restrict__ fc2_b,
    float* __restrict__ out, char* ws)
{
  const int cl = blockIdx.x & 7, wg = blockIdx.x >> 3;
  const int tid = threadIdx.x;
  const int wv = tid >> 6, l = tid & 63;
  const int m = wv >> 1, nh = wv & 1;
  const int hi = l >> 4, lr = l & 15;
  const int nt0 = nh * 2, nt1 = nh * 2 + 1;

  u32* flags = (u32*)ws;
  char* cbase = ws + 16 * 1024 + cl * CLSTRIDE;
  f16*   xb   = (f16*)(cbase);
  f16*   h1b  = (f16*)(cbase + 32 * 1024);
  f16*   h2b  = (f16*)(cbase + 96 * 1024);
  float* part = (float*)(cbase + 160 * 1024);
  const f16* zp = (const f16*)(ws + ZPROJ_OFF);

  // ----- static per-thread data -----
  const int hid_loc = m * 4 + hi;            // 0..7 within WG
  const int H = wg * 8 + hid_loc;            // absolute hid
  const int r_loc = m * 16 + lr;             // local gate row (A-frag row)
  const int R = (r_loc & 3) * 256 + wg * 8 + (r_loc >> 2);  // abs gate row

  f16x8 w1f[16], w2f[16];                    // K=512 -> 16 ksteps
  #pragma unroll
  for (int ks = 0; ks < 16; ++ks) {
    const int ko = (ks & 7) * 32 + hi * 8;
    const float* s1 = (ks < 8) ? (w_ih1 + R * 256 + ko) : (w_hh1 + R * 256 + ko);
    const float* s2 = (ks < 8) ? (w_ih2 + R * 256 + ko) : (w_hh2 + R * 256 + ko);
    f16x8 a, b;
    #pragma unroll
    for (int j = 0; j < 8; ++j) { a[j] = (f16)s1[j]; b[j] = (f16)s2[j]; }
    w1f[ks] = a; w2f[ks] = b;
  }

  float bs1[4], bs2[4];
  #pragma unroll
  for (int gg = 0; gg < 4; ++gg) {
    bs1[gg] = b_ih1[gg * 256 + H] + b_hh1[gg * 256 + H];
    bs2[gg] = b_ih2[gg * 256 + H] + b_hh2[gg * 256 + H];
  }
  float f2w[5];
  #pragma unroll
  for (int r = 0; r < 5; ++r) f2w[r] = fc2_w[r * 256 + H];

  // stage-C thread mapping
  const int bC = tid & 63, rgC = tid >> 6;
  float w1p[2][5], b1c[2];
  #pragma unroll
  for (int rr = 0; rr < 2; ++rr) {
    const int xr = wg * 8 + rgC * 2 + rr;
    #pragma unroll
    for (int p = 0; p < 5; ++p) w1p[rr][p] = fc1_w[xr * 105 + 100 + p];
    b1c[rr] = fc1_b[xr];
  }

  __shared__ alignas(16) f16 hstage[64][8];
  __shared__ float prevlds[5][64];

  float c1a = 0.f, c1b = 0.f, c2a = 0.f, c2b = 0.f;
  const int bbase = cl * 64;
  u32 phase = 0;

  for (int t = 0; t < SEQ; ++t) {
    // ================= stage C: prev_{t-1} + x_t =================
    if (t == 0) {
      prevlds[rgC][bC] = prev_gen[(bbase + bC) * 5 + rgC];
      if (rgC == 0) prevlds[4][bC] = prev_gen[(bbase + bC) * 5 + 4];
    } else {
      float s = 0.f;
      #pragma unroll 8
      for (int p = 0; p < 64; ++p) s += part[(p * 5 + rgC) * 64 + bC];
      s = ftanh(s + fc2_b[rgC]);
      prevlds[rgC][bC] = s;
      if (wg == 0) out[((long)(bbase + bC) * SEQ + (t - 1)) * 5 + rgC] = s;
      if (rgC == 0) {
        float s4 = 0.f;
        #pragma unroll 8
        for (int p = 0; p < 64; ++p) s4 += part[(p * 5 + 4) * 64 + bC];
        s4 = ftanh(s4 + fc2_b[4]);
        prevlds[4][bC] = s4;
        if (wg == 0) out[((long)(bbase + bC) * SEQ + (t - 1)) * 5 + 4] = s4;
      }
    }
    __syncthreads();
    {
      const f16* zrow = zp + ((long)(bbase + bC) * SEQ + t) * 256 + wg * 8 + rgC * 2;
      float pv[5];
      #pragma unroll
      for (int p = 0; p < 5; ++p) pv[p] = prevlds[p][bC];
      #pragma unroll
      for (int rr = 0; rr < 2; ++rr) {
        float v = (float)zrow[rr] + b1c[rr];
        #pragma unroll
        for (int p = 0; p < 5; ++p) v += w1p[rr][p] * pv[p];
        hstage[bC][rgC * 2 + rr] = (f16)fmaxf(v, 0.f);
      }
    }
    __syncthreads();
    if (tid < 64)
      push_f16x8(xb + tid * 256 + wg * 8, hstage[tid]);
    cluster_barrier(flags, cl, wg, ++phase, tid);

    // ================= stage A: gates1 -> h1_t =================
    {
      const f16* hprev = h1b + ((t + 1) & 1) * (64 * 256);
      f32x4 acc0 = {0.f, 0.f, 0.f, 0.f}, acc1 = {0.f, 0.f, 0.f, 0.f};
      #pragma unroll
      for (int ks = 0; ks < 16; ++ks) {
        const f16* src = (ks < 8) ? xb : hprev;
        const int koff = (ks & 7) * 32 + hi * 8;
        f16x8 b0 = *(const f16x8*)(src + (nt0 * 16 + lr) * 256 + koff);
        f16x8 b1 = *(const f16x8*)(src + (nt1 * 16 + lr) * 256 + koff);
        acc0 = __builtin_amdgcn_mfma_f32_16x16x32_f16(w1f[ks], b0, acc0, 0, 0, 0);
        acc1 = __builtin_amdgcn_mfma_f32_16x16x32_f16(w1f[ks], b1, acc1, 0, 0, 0);
      }
      float i0 = fsig(acc0[0] + bs1[0]), f0 = fsig(acc0[1] + bs1[1]);
      float g0 = ftanh(acc0[2] + bs1[2]), o0 = fsig(acc0[3] + bs1[3]);
      c1a = f0 * c1a + i0 * g0;
      hstage[nt0 * 16 + lr][hid_loc] = (f16)(o0 * ftanh(c1a));
      float i1 = fsig(acc1[0] + bs1[0]), f1 = fsig(acc1[1] + bs1[1]);
      float g1 = ftanh(acc1[2] + bs1[2]), o1 = fsig(acc1[3] + bs1[3]);
      c1b = f1 * c1b + i1 * g1;
      hstage[nt1 * 16 + lr][hid_loc] = (f16)(o1 * ftanh(c1b));
    }
    __syncthreads();
    if (tid < 64)
      push_f16x8(h1b + (t & 1) * (64 * 256) + tid * 256 + wg * 8, hstage[tid]);
    cluster_barrier(flags, cl, wg, ++phase, tid);

    // ================= stage B: gates2 -> h2_t + fc2 partials =================
    {
      const f16* h1cur  = h1b + (t & 1) * (64 * 256);
      const f16* h2prev = h2b + ((t + 1) & 1) * (64 * 256);
      f32x4 acc0 = {0.f, 0.f, 0.f, 0.f}, acc1 = {0.f, 0.f, 0.f, 0.f};
      #pragma unroll
      for (int ks = 0; ks < 16; ++ks) {
        const f16* src = (ks < 8) ? h1cur : h2prev;
        const int koff = (ks & 7) * 32 + hi * 8;
        f16x8 b0 = *(const f16x8*)(src + (nt0 * 16 + lr) * 256 + koff);
        f16x8 b1 = *(const f16x8*)(src + (nt1 * 16 + lr) * 256 + koff);
        acc0 = __builtin_amdgcn_mfma_f32_16x16x32_f16(w2f[ks], b0, acc0, 0, 0, 0);
        acc1 = __builtin_amdgcn_mfma_f32_16x16x32_f16(w2f[ks], b1, acc1, 0, 0, 0);
      }
      float i0 = fsig(acc0[0] + bs2[0]), f0 = fsig(acc0[1] + bs2[1]);
      float g0 = ftanh(acc0[2] + bs2[2]), o0 = fsig(acc0[3] + bs2[3]);
      c2a = f0 * c2a + i0 * g0;
      float hv0 = o0 * ftanh(c2a);
      float i1 = fsig(acc1[0] + bs2[0]), f1 = fsig(acc1[1] + bs2[1]);
      float g1 = ftanh(acc1[2] + bs2[2]), o1 = fsig(acc1[3] + bs2[3]);
      c2b = f1 * c2b + i1 * g1;
      float hv1 = o1 * ftanh(c2b);
      hstage[nt0 * 16 + lr][hid_loc] = (f16)hv0;
      hstage[nt1 * 16 + lr][hid_loc] = (f16)hv1;

      // fc2 partials from fp32 register h2
      float p0[5], p1[5];
      #pragma unroll
      for (int r = 0; r < 5; ++r) { p0[r] = f2w[r] * hv0; p1[r] = f2w[r] * hv1; }
      #pragma unroll
      for (int r = 0; r < 5; ++r) {
        p0[r] += __shfl_xor(p0[r], 16); p0[r] += __shfl_xor(p0[r], 32);
        p1[r] += __shfl_xor(p1[r], 16); p1[r] += __shfl_xor(p1[r], 32);
      }
      if (hi == 0) {
        const int slot = wg * 2 + m;
        #pragma unroll
        for (int r = 0; r < 5; ++r) {
          push_f32(&part[(slot * 5 + r) * 64 + nt0 * 16 + lr], p0[r]);
          push_f32(&part[(slot * 5 + r) * 64 + nt1 * 16 + lr], p1[r]);
        }
      }
    }
    __syncthreads();
    if (tid < 64)
      push_f16x8(h2b + (t & 1) * (64 * 256) + tid * 256 + wg * 8, hstage[tid]);
    cluster_barrier(flags, cl, wg, ++phase, tid);
  }

  // ================= final output: prev_600 =================
  {
    float s = 0.f;
    #pragma unroll 8
    for (int p = 0; p < 64; ++p) s += part[(p * 5 + rgC) * 64 + bC];
    s = ftanh(s + fc2_b[rgC]);
    if (wg == 0) out[((long)(bbase + bC) * SEQ + (SEQ - 1)) * 5 + rgC] = s;
    if (rgC == 0) {
      float s4 = 0.f;
      #pragma unroll 8
      for (int p = 0; p < 64; ++p) s4 += part[(p * 5 + 4) * 64 + bC];
      s4 = ftanh(s4 + fc2_b[4]);
      if (wg == 0) out[((long)(bbase + bC) * SEQ + (SEQ - 1)) * 5 + 4] = s4;
    }
  }
}

// ---------------- launcher ----------------
extern "C" void kernel_launch(void* const* d_in, const int* in_sizes, int n_in,
                              void* d_out, int out_size, void* d_ws, size_t ws_size,
                              hipStream_t stream)
{
  const float* z     = (const float*)d_in[0];
  const float* prevg = (const float*)d_in[1];
  const float* fc1_w = (const float*)d_in[2];
  const float* fc1_b = (const float*)d_in[3];
  const float* w_ih1 = (const float*)d_in[4];
  const float* w_hh1 = (const float*)d_in[5];
  const float* b_ih1 = (const float*)d_in[6];
  const float* b_hh1 = (const float*)d_in[7];
  const float* w_ih2 = (const float*)d_in[8];
  const float* w_hh2 = (const float*)d_in[9];
  const float* b_ih2 = (const float*)d_in[10];
  const float* b_hh2 = (const float*)d_in[11];
  const float* fc2_w = (const float*)d_in[12];
  const float* fc2_b = (const float*)d_in[13];
  float* out = (float*)d_out;
  char*  ws  = (char*)d_ws;

  // zero flags + exchange buffers (h_{-1}=0, and kills the 0xAA poison)
  hipMemsetAsync(ws, 0, CTRL_BYTES, stream);

  f16* zproj = (f16*)(ws + ZPROJ_OFF);
  zproj_kernel<<<dim3(4808), dim3(256), 0, stream>>>(z, fc1_w, zproj);

  rnn_kernel<<<dim3(256), dim3(256), 0, stream>>>(
      prevg, fc1_w, fc1_b, w_ih1, w_hh1, b_ih1, b_hh1,
      w_ih2, w_hh2, b_ih2, b_hh2, fc2_w, fc2_b, out, ws);
}

// Round 9
// 15416.872 us; speedup vs baseline: 163.7820x; 1.6026x over previous
//
#include <hip/hip_runtime.h>

// ---------------- problem constants ----------------
#define SEQ   601
#define NCL   8          // clusters (64 batch rows each)
#define WPC   32         // workgroups per cluster (8 hid units each)

typedef _Float16 f16;
typedef _Float16 f16x8 __attribute__((ext_vector_type(8)));
typedef _Float16 f16x4 __attribute__((ext_vector_type(4)));
typedef float    f32x4 __attribute__((ext_vector_type(4)));
typedef unsigned int u32;
typedef unsigned long long u64;

// ---------------- workspace layout (bytes) ----------------
// [0, 4K)                 counters: [8 cl], each on its own 64B line
// 4K + cl*CLSTRIDE:
//    +0      h1b [2 buf][32 kb][64 row][8] f16   64K   (kb = hid/8 block)
//    +64K    h2b [2 buf][32 kb][64 row][8] f16   64K
// Blocked layout: WG wg pushes its 1KB slice CONTIGUOUSLY at [buf][wg][*][*]
// (full 64B lines -> no fabric read-modify-write, unlike R5's 16B-per-line
// scatter that inflated WRITE_SIZE to 2.25 GB).
#define CLSTRIDE   131072
#define CTRL_BYTES (4096 + NCL * CLSTRIDE)
#define ZPROJ_OFF  (2 * 1024 * 1024)   // zproj: [512*601][256] f16 = 157.5MB

#define HBUF 16384   // f16 elements per h-buffer (32*64*8)

// ---------------- fast math ----------------
__device__ __forceinline__ float fsig(float x) { return 1.0f / (1.0f + __expf(-x)); }
__device__ __forceinline__ float ftanh(float x) { return 1.0f - 2.0f / (__expf(2.0f * x) + 1.0f); }

// ---------------- coherence-point push stores ----------------
// Relaxed agent-scope atomic store: write-through to the device coherence
// point, no fence emitted (R1 measured the fence path = full-L2 writeback).
__device__ __forceinline__ void push_u64(u64* p, u64 v) {
  __hip_atomic_store(p, v, __ATOMIC_RELAXED, __HIP_MEMORY_SCOPE_AGENT);
}
__device__ __forceinline__ void push_f16x8(f16* dst, const f16* src) {
  u64 lo, hi;
  __builtin_memcpy(&lo, src, 8);
  __builtin_memcpy(&hi, src + 4, 8);
  push_u64((u64*)dst, lo);
  push_u64((u64*)dst + 1, hi);
}

// ---------------- cluster barrier (centralized atomic counter) ----------------
// One atomic add + one single-lane poll line per cluster (R5's 32-lane x
// 32-line poll fanned 2KB of fabric reads per poll round). Monotonic target
// phase*WPC; counters zeroed by hipMemsetAsync (0xAA poison can't satisfy).
// Data visibility: sc1 pushes acked at coherence point before __syncthreads
// lets tid 0 post; acquire-agent fence after join (buffer_inv, no writeback)
// so plain reads of exchange buffers refetch fresh lines.
__device__ __forceinline__ void cluster_barrier(u32* ctr, int cl, u32 phase, int tid) {
  __syncthreads();
  if (tid == 0) {
    u32* c = &ctr[cl * 16];
    __hip_atomic_fetch_add(c, 1u, __ATOMIC_RELAXED, __HIP_MEMORY_SCOPE_AGENT);
    const u32 target = phase * WPC;
    int guard = 0;
    while (__hip_atomic_load(c, __ATOMIC_RELAXED, __HIP_MEMORY_SCOPE_AGENT) < target) {
      __builtin_amdgcn_s_sleep(2);
      if (++guard >= (1 << 15)) break;   // fail-fast tripwire
    }
  }
  __syncthreads();
  __builtin_amdgcn_fence(__ATOMIC_ACQUIRE, "agent");
}

// ---------------- zproj kernel (folds fc1_b) ----------------
// zproj[col][row] = sum_{k<100} fc1_w[row][k]*z[col][k] + fc1_b[row]
__global__ __launch_bounds__(256) void zproj_kernel(
    const float* __restrict__ z, const float* __restrict__ fc1_w,
    const float* __restrict__ fc1_b, f16* __restrict__ zp)
{
  const int wv = threadIdx.x >> 6, l = threadIdx.x & 63;
  const int hi = l >> 4, lr = l & 15;
  const long col = (long)blockIdx.x * 64 + wv * 16 + lr;

  f16x8 zf[4];
  {
    const float* zr = z + col * 100;
    #pragma unroll
    for (int ks = 0; ks < 4; ++ks) {
      const int kb = ks * 32 + hi * 8;
      f16x8 v;
      #pragma unroll
      for (int j = 0; j < 8; ++j) {
        const int k = kb + j;
        float x = (k < 100) ? zr[k] : 0.0f;
        v[j] = (f16)x;
      }
      zf[ks] = v;
    }
  }

  f32x4 acc[16];
  #pragma unroll
  for (int mt = 0; mt < 16; ++mt) acc[mt] = (f32x4){0.f, 0.f, 0.f, 0.f};

  #pragma unroll
  for (int mt = 0; mt < 16; ++mt) {
    const int row = mt * 16 + lr;
    const float* wr = fc1_w + row * 105;
    #pragma unroll
    for (int ks = 0; ks < 4; ++ks) {
      const int kb = ks * 32 + hi * 8;
      f16x8 wf;
      #pragma unroll
      for (int j = 0; j < 8; ++j) {
        const int k = kb + j;
        float x = (k < 100) ? wr[k] : 0.0f;
        wf[j] = (f16)x;
      }
      acc[mt] = __builtin_amdgcn_mfma_f32_16x16x32_f16(wf, zf[ks], acc[mt], 0, 0, 0);
    }
  }

  // C layout: col = l&15, row = 16*mt + 4*hi + jj
  f16* outp = zp + col * 256;
  #pragma unroll
  for (int mt = 0; mt < 16; ++mt) {
    f16x4 v;
    #pragma unroll
    for (int jj = 0; jj < 4; ++jj)
      v[jj] = (f16)(acc[mt][jj] + fc1_b[mt * 16 + hi * 4 + jj]);
    *(f16x4*)(outp + mt * 16 + hi * 4) = v;
  }
}

// ---------------- main persistent recurrence kernel ----------------
// 256 WGs x 256 thr, 1 WG/CU. cluster = blockIdx&7 (64 batch rows),
// wg = blockIdx>>3 (8 hid units of both cells). TWO barriers per step:
//   CA: fc2(h2_{t-1}) -> prev (redundant per WG, no part exchange);
//       x_t computed redundantly into LDS (no x all-gather);
//       gates1 (B: x from LDS, h1prev global) -> h1 push -> barrier
//   B:  gates2 (B: h1cur global, h2prev from LDS stash) -> h2 push -> barrier
__global__ __launch_bounds__(256, 1) void rnn_kernel(
    const float* __restrict__ prev_gen,
    const float* __restrict__ fc1_w, const float* __restrict__ fc1_b,
    const float* __restrict__ w_ih1, const float* __restrict__ w_hh1,
    const float* __restrict__ b_ih1, const float* __restrict__ b_hh1,
    const float* __restrict__ w_ih2, const float* __restrict__ w_hh2,
    const float* __restrict__ b_ih2, const float* __restrict__ b_hh2,
    const float* __restrict__ fc2_w, const float* __restrict__ fc2_b,
    float* __restrict__ out, char* ws)
{
  const int cl = blockIdx.x & 7, wg = blockIdx.x >> 3;
  const int tid = threadIdx.x;
  const int wv = tid >> 6, l = tid & 63;
  const int m = wv >> 1, nh = wv & 1;
  const int hi = l >> 4, lr = l & 15;
  const int nt0 = nh * 2, nt1 = nh * 2 + 1;
  const int bC6 = tid & 63, q4 = tid >> 6;   // fc2/x-compute mapping

  u32* ctr = (u32*)ws;
  char* cbase = ws + 4096 + cl * CLSTRIDE;
  f16* h1b = (f16*)(cbase);
  f16* h2b = (f16*)(cbase + 65536);
  const f16* zp = (const f16*)(ws + ZPROJ_OFF);

  // ----- static per-thread data (identical packing to verified R5) -----
  const int hid_loc = m * 4 + hi;
  const int H = wg * 8 + hid_loc;
  const int r_loc = m * 16 + lr;
  const int R = (r_loc & 3) * 256 + wg * 8 + (r_loc >> 2);

  f16x8 w1f[16], w2f[16];
  #pragma unroll
  for (int ks = 0; ks < 16; ++ks) {
    const int ko = (ks & 7) * 32 + hi * 8;
    const float* s1 = (ks < 8) ? (w_ih1 + R * 256 + ko) : (w_hh1 + R * 256 + ko);
    const float* s2 = (ks < 8) ? (w_ih2 + R * 256 + ko) : (w_hh2 + R * 256 + ko);
    f16x8 a, b;
    #pragma unroll
    for (int j = 0; j < 8; ++j) { a[j] = (f16)s1[j]; b[j] = (f16)s2[j]; }
    w1f[ks] = a; w2f[ks] = b;
  }
  float bs1[4], bs2[4];
  #pragma unroll
  for (int gg = 0; gg < 4; ++gg) {
    bs1[gg] = b_ih1[gg * 256 + H] + b_hh1[gg * 256 + H];
    bs2[gg] = b_ih2[gg * 256 + H] + b_hh2[gg * 256 + H];
  }

  // ----- LDS -----
  __shared__ alignas(16) f16 x_lds[64][264];    // +8 pad: breaks 16-way conflicts
  __shared__ alignas(16) f16 h2lds[64][264];    // h2_{t-1} stash
  __shared__ float w1v[5][256];                 // fc1_w prev-part, [r][hid]
  __shared__ float fc2v[5][256];                // fc2_w, [r][hid]
  __shared__ float prevlds[64][5];
  __shared__ float plds[4][64][5];
  __shared__ alignas(16) f16 hstage[64][8];

  {
    const int h = tid;
    #pragma unroll
    for (int r = 0; r < 5; ++r) {
      w1v[r][h]  = fc1_w[h * 105 + 100 + r];
      fc2v[r][h] = fc2_w[r * 256 + h];
    }
    f16* h2f = &h2lds[0][0];
    for (int i = tid; i < 64 * 264; i += 256) h2f[i] = (f16)0.0f;  // h2_{-1}=0
  }
  __syncthreads();

  float c1a = 0.f, c1b = 0.f, c2a = 0.f, c2b = 0.f;
  const int bbase = cl * 64;
  u32 phase = 0;

  for (int t = 0; t < SEQ; ++t) {
    // ============ stage CA part 1: prev_{t-1} via fc2(h2_{t-1}) ============
    if (t == 0) {
      if (tid < 64) {
        #pragma unroll
        for (int r = 0; r < 5; ++r)
          prevlds[tid][r] = prev_gen[(bbase + tid) * 5 + r];
      }
    } else {
      const f16* h2src = h2b + ((t + 1) & 1) * HBUF;
      float pr[5] = {0.f, 0.f, 0.f, 0.f, 0.f};
      #pragma unroll
      for (int c = 0; c < 8; ++c) {
        const int kb = q4 * 8 + c;
        f16x8 hv = *(const f16x8*)(h2src + (kb * 64 + bC6) * 8);  // coalesced
        *(f16x8*)&h2lds[bC6][kb * 8] = hv;                        // stash for gates2
        float hf[8];
        #pragma unroll
        for (int j = 0; j < 8; ++j) hf[j] = (float)hv[j];
        #pragma unroll
        for (int r = 0; r < 5; ++r) {
          f32x4 wa = *(const f32x4*)&fc2v[r][kb * 8];       // broadcast (lanes share q4)
          f32x4 wb = *(const f32x4*)&fc2v[r][kb * 8 + 4];
          pr[r] += hf[0]*wa[0] + hf[1]*wa[1] + hf[2]*wa[2] + hf[3]*wa[3]
                 + hf[4]*wb[0] + hf[5]*wb[1] + hf[6]*wb[2] + hf[7]*wb[3];
        }
      }
      #pragma unroll
      for (int r = 0; r < 5; ++r) plds[q4][bC6][r] = pr[r];
      __syncthreads();
      if (tid < 64) {
        #pragma unroll
        for (int r = 0; r < 5; ++r) {
          float s = plds[0][tid][r] + plds[1][tid][r] + plds[2][tid][r] + plds[3][tid][r];
          s = ftanh(s + fc2_b[r]);
          prevlds[tid][r] = s;
          if (wg == 0) out[((long)(bbase + tid) * SEQ + (t - 1)) * 5 + r] = s;
        }
      }
    }
    __syncthreads();

    // ============ stage CA part 2: x_t (redundant per WG, no all-gather) ====
    {
      const f16* zrow = zp + ((long)(bbase + bC6) * SEQ + t) * 256 + q4 * 64;
      float pv[5];
      #pragma unroll
      for (int r = 0; r < 5; ++r) pv[r] = prevlds[bC6][r];
      #pragma unroll
      for (int c = 0; c < 8; ++c) {
        f16x8 zv = *(const f16x8*)(zrow + c * 8);
        const int hbase = q4 * 64 + c * 8;
        f16x8 xo;
        #pragma unroll
        for (int j = 0; j < 8; ++j) {
          float v = (float)zv[j];   // zproj already includes fc1_b
          #pragma unroll
          for (int r = 0; r < 5; ++r) v += pv[r] * w1v[r][hbase + j];
          xo[j] = (f16)fmaxf(v, 0.f);
        }
        *(f16x8*)&x_lds[bC6][hbase] = xo;
      }
    }
    __syncthreads();

    // ============ stage CA part 3: gates1 -> h1_t ============
    {
      const f16* h1prev = h1b + ((t + 1) & 1) * HBUF;
      f32x4 acc0 = {0.f, 0.f, 0.f, 0.f}, acc1 = {0.f, 0.f, 0.f, 0.f};
      #pragma unroll
      for (int ks = 0; ks < 8; ++ks) {   // x-part from LDS
        const int koff = ks * 32 + hi * 8;
        f16x8 b0 = *(const f16x8*)&x_lds[nt0 * 16 + lr][koff];
        f16x8 b1 = *(const f16x8*)&x_lds[nt1 * 16 + lr][koff];
        acc0 = __builtin_amdgcn_mfma_f32_16x16x32_f16(w1f[ks], b0, acc0, 0, 0, 0);
        acc1 = __builtin_amdgcn_mfma_f32_16x16x32_f16(w1f[ks], b1, acc1, 0, 0, 0);
      }
      #pragma unroll
      for (int ks = 8; ks < 16; ++ks) {  // h-part from blocked global
        const int kb = (ks - 8) * 4 + hi;
        f16x8 b0 = *(const f16x8*)(h1prev + (kb * 64 + nt0 * 16 + lr) * 8);
        f16x8 b1 = *(const f16x8*)(h1prev + (kb * 64 + nt1 * 16 + lr) * 8);
        acc0 = __builtin_amdgcn_mfma_f32_16x16x32_f16(w1f[ks], b0, acc0, 0, 0, 0);
        acc1 = __builtin_amdgcn_mfma_f32_16x16x32_f16(w1f[ks], b1, acc1, 0, 0, 0);
      }
      float i0 = fsig(acc0[0] + bs1[0]), f0 = fsig(acc0[1] + bs1[1]);
      float g0 = ftanh(acc0[2] + bs1[2]), o0 = fsig(acc0[3] + bs1[3]);
      c1a = f0 * c1a + i0 * g0;
      hstage[nt0 * 16 + lr][hid_loc] = (f16)(o0 * ftanh(c1a));
      float i1 = fsig(acc1[0] + bs1[0]), f1 = fsig(acc1[1] + bs1[1]);
      float g1 = ftanh(acc1[2] + bs1[2]), o1 = fsig(acc1[3] + bs1[3]);
      c1b = f1 * c1b + i1 * g1;
      hstage[nt1 * 16 + lr][hid_loc] = (f16)(o1 * ftanh(c1b));
    }
    __syncthreads();
    if (tid < 64)   // contiguous 1KB block push (full lines)
      push_f16x8(h1b + (t & 1) * HBUF + wg * 512 + tid * 8, hstage[tid]);
    cluster_barrier(ctr, cl, ++phase, tid);

    // ============ stage B: gates2 -> h2_t ============
    {
      const f16* h1cur = h1b + (t & 1) * HBUF;
      f32x4 acc0 = {0.f, 0.f, 0.f, 0.f}, acc1 = {0.f, 0.f, 0.f, 0.f};
      #pragma unroll
      for (int ks = 0; ks < 8; ++ks) {   // h1-part from blocked global
        const int kb = ks * 4 + hi;
        f16x8 b0 = *(const f16x8*)(h1cur + (kb * 64 + nt0 * 16 + lr) * 8);
        f16x8 b1 = *(const f16x8*)(h1cur + (kb * 64 + nt1 * 16 + lr) * 8);
        acc0 = __builtin_amdgcn_mfma_f32_16x16x32_f16(w2f[ks], b0, acc0, 0, 0, 0);
        acc1 = __builtin_amdgcn_mfma_f32_16x16x32_f16(w2f[ks], b1, acc1, 0, 0, 0);
      }
      #pragma unroll
      for (int ks = 8; ks < 16; ++ks) {  // h2prev from LDS stash
        const int koff = (ks - 8) * 32 + hi * 8;
        f16x8 b0 = *(const f16x8*)&h2lds[nt0 * 16 + lr][koff];
        f16x8 b1 = *(const f16x8*)&h2lds[nt1 * 16 + lr][koff];
        acc0 = __builtin_amdgcn_mfma_f32_16x16x32_f16(w2f[ks], b0, acc0, 0, 0, 0);
        acc1 = __builtin_amdgcn_mfma_f32_16x16x32_f16(w2f[ks], b1, acc1, 0, 0, 0);
      }
      float i0 = fsig(acc0[0] + bs2[0]), f0 = fsig(acc0[1] + bs2[1]);
      float g0 = ftanh(acc0[2] + bs2[2]), o0 = fsig(acc0[3] + bs2[3]);
      c2a = f0 * c2a + i0 * g0;
      hstage[nt0 * 16 + lr][hid_loc] = (f16)(o0 * ftanh(c2a));
      float i1 = fsig(acc1[0] + bs2[0]), f1 = fsig(acc1[1] + bs2[1]);
      float g1 = ftanh(acc1[2] + bs2[2]), o1 = fsig(acc1[3] + bs2[3]);
      c2b = f1 * c2b + i1 * g1;
      hstage[nt1 * 16 + lr][hid_loc] = (f16)(o1 * ftanh(c2b));
    }
    __syncthreads();
    if (tid < 64)
      push_f16x8(h2b + (t & 1) * HBUF + wg * 512 + tid * 8, hstage[tid]);
    cluster_barrier(ctr, cl, ++phase, tid);
  }

  // ============ final output: prev_600 = tanh(fc2(h2_600)) ============
  {
    const f16* h2src = h2b + ((SEQ + 1) & 1) * HBUF;  // buffer written at t=600
    float pr[5] = {0.f, 0.f, 0.f, 0.f, 0.f};
    #pragma unroll
    for (int c = 0; c < 8; ++c) {
      const int kb = q4 * 8 + c;
      f16x8 hv = *(const f16x8*)(h2src + (kb * 64 + bC6) * 8);
      float hf[8];
      #pragma unroll
      for (int j = 0; j < 8; ++j) hf[j] = (float)hv[j];
      #pragma unroll
      for (int r = 0; r < 5; ++r) {
        f32x4 wa = *(const f32x4*)&fc2v[r][kb * 8];
        f32x4 wb = *(const f32x4*)&fc2v[r][kb * 8 + 4];
        pr[r] += hf[0]*wa[0] + hf[1]*wa[1] + hf[2]*wa[2] + hf[3]*wa[3]
               + hf[4]*wb[0] + hf[5]*wb[1] + hf[6]*wb[2] + hf[7]*wb[3];
      }
    }
    #pragma unroll
    for (int r = 0; r < 5; ++r) plds[q4][bC6][r] = pr[r];
    __syncthreads();
    if (wg == 0 && tid < 64) {
      #pragma unroll
      for (int r = 0; r < 5; ++r) {
        float s = plds[0][tid][r] + plds[1][tid][r] + plds[2][tid][r] + plds[3][tid][r];
        out[((long)(bbase + tid) * SEQ + (SEQ - 1)) * 5 + r] = ftanh(s + fc2_b[r]);
      }
    }
  }
}

// ---------------- launcher ----------------
extern "C" void kernel_launch(void* const* d_in, const int* in_sizes, int n_in,
                              void* d_out, int out_size, void* d_ws, size_t ws_size,
                              hipStream_t stream)
{
  const float* z     = (const float*)d_in[0];
  const float* prevg = (const float*)d_in[1];
  const float* fc1_w = (const float*)d_in[2];
  const float* fc1_b = (const float*)d_in[3];
  const float* w_ih1 = (const float*)d_in[4];
  const float* w_hh1 = (const float*)d_in[5];
  const float* b_ih1 = (const float*)d_in[6];
  const float* b_hh1 = (const float*)d_in[7];
  const float* w_ih2 = (const float*)d_in[8];
  const float* w_hh2 = (const float*)d_in[9];
  const float* b_ih2 = (const float*)d_in[10];
  const float* b_hh2 = (const float*)d_in[11];
  const float* fc2_w = (const float*)d_in[12];
  const float* fc2_b = (const float*)d_in[13];
  float* out = (float*)d_out;
  char*  ws  = (char*)d_ws;

  // zero counters + h-buffers (h_{-1}=0, kills the 0xAA poison)
  hipMemsetAsync(ws, 0, CTRL_BYTES, stream);

  f16* zproj = (f16*)(ws + ZPROJ_OFF);
  zproj_kernel<<<dim3(4808), dim3(256), 0, stream>>>(z, fc1_w, fc1_b, zproj);

  rnn_kernel<<<dim3(256), dim3(256), 0, stream>>>(
      prevg, fc1_w, fc1_b, w_ih1, w_hh1, b_ih1, b_hh1,
      w_ih2, w_hh2, b_ih2, b_hh2, fc2_w, fc2_b, out, ws);
}